// Round 2
// baseline (628.400 us; speedup 1.0000x reference)
//
#include <hip/hip_runtime.h>
#include <hip/hip_bf16.h>

typedef float f32x4 __attribute__((ext_vector_type(4)));
typedef __bf16 bf16x8 __attribute__((ext_vector_type(8)));

#define MFMA(a,b,c) __builtin_amdgcn_mfma_f32_16x16x32_bf16(a,b,c,0,0,0)

// workspace layout (bytes)
#define WS_A_BF   0x000000   // bf16 8192*128  (h@W1a + edge_b1)
#define WS_B_BF   0x200000   // bf16 8192*128  (h@W1b)
#define WS_W2T    0x400000   // bf16 128*128   edge_w2^T
#define WS_C1T    0x408000   // bf16 128*128   coord_w1^T
#define WS_W1AT   0x410000   // bf16 128*128   edge_w1[0:128]^T
#define WS_W1BT   0x418000   // bf16 128*128   edge_w1[128:256]^T
#define WS_VW1T   0x420000   // bf16 128*128   velm_w1^T
#define WS_MW2T   0x428000   // bf16 128*128   mlp_w2^T
#define WS_EWT    0x430000   // bf16 128*32    embed_w^T (K padded 30->32)
#define WS_MW1T   0x432000   // bf16 128*64    mlp_w1^T  (K padded 34->64)
#define WS_W1S    0x436000   // bf16 128       edge_w1 row256+row257
#define WS_BASE   0x436200   // f32 8192*2     vel_scale*vel + zMLP

// fast silu: single-instruction v_exp / v_rcp (bf16-accuracy is plenty;
// IEEE div was a ~10-instr v_div_* sequence dominating VALU)
static __device__ __forceinline__ float silu_f(float x) {
  float e = __expf(-x);
  return x * __builtin_amdgcn_rcpf(1.0f + e);
}

// ---------------- kernel 0: weight prep (transpose to [out][in], bf16) --------
__global__ void k_prep(const float* __restrict__ ew1, const float* __restrict__ ew2,
                       const float* __restrict__ cw1, const float* __restrict__ vw1,
                       const float* __restrict__ mw1, const float* __restrict__ mw2,
                       const float* __restrict__ embw, char* __restrict__ ws) {
  int n = blockIdx.x;   // 0..127 : output row
  int k = threadIdx.x;  // 0..127 : input col
  ((__bf16*)(ws+WS_W2T ))[n*128+k] = (__bf16)ew2[k*128+n];
  ((__bf16*)(ws+WS_C1T ))[n*128+k] = (__bf16)cw1[k*128+n];
  ((__bf16*)(ws+WS_W1AT))[n*128+k] = (__bf16)ew1[k*128+n];
  ((__bf16*)(ws+WS_W1BT))[n*128+k] = (__bf16)ew1[(128+k)*128+n];
  ((__bf16*)(ws+WS_VW1T))[n*128+k] = (__bf16)vw1[k*128+n];
  ((__bf16*)(ws+WS_MW2T))[n*128+k] = (__bf16)mw2[k*128+n];
  if (k < 32) ((__bf16*)(ws+WS_EWT ))[n*32+k] = (k<30) ? (__bf16)embw[k*128+n] : (__bf16)0.0f;
  if (k < 64) ((__bf16*)(ws+WS_MW1T))[n*64+k] = (k<34) ? (__bf16)mw1[k*128+n] : (__bf16)0.0f;
  if (n == 0) ((__bf16*)(ws+WS_W1S))[k] = (__bf16)(ew1[256*128+k] + ew1[257*128+k]);
}

// ---------------- kernel 1: node-level (h, A_pre, B_pre, vel_scale, zMLP) -----
// 128 blocks x 256 threads; each wave handles 16 nodes. No barriers needed:
// the hw scratch is per-wave private.
__global__ __launch_bounds__(256) void k_node(
    const float* __restrict__ obs,
    const float* __restrict__ emb_b,   const float* __restrict__ edge_b1,
    const float* __restrict__ velm_b1, const float* __restrict__ velm_w2,
    const float* __restrict__ velm_b2, const float* __restrict__ mlp_b1,
    const float* __restrict__ mlp_b2,  const float* __restrict__ mlp_w3,
    const float* __restrict__ mlp_b3,  char* __restrict__ ws) {
  __shared__ char hsh_all[4*4096];
  const int tid = threadIdx.x;
  const int wid = tid>>6, lane = tid&63, lgrp = lane>>4, lid = lane&15;
  char* hw = hsh_all + wid*4096;   // 16 rows x 256B per wave
  const int nb = blockIdx.x*64 + wid*16;
  const int node = nb + lid;

  const __bf16* EWT  = (const __bf16*)(ws+WS_EWT);
  const __bf16* W1AT = (const __bf16*)(ws+WS_W1AT);
  const __bf16* W1BT = (const __bf16*)(ws+WS_W1BT);
  const __bf16* VW1T = (const __bf16*)(ws+WS_VW1T);
  const __bf16* MW1T = (const __bf16*)(ws+WS_MW1T);
  const __bf16* MW2T = (const __bf16*)(ws+WS_MW2T);
  __bf16* A_bf = (__bf16*)(ws+WS_A_BF);
  __bf16* B_bf = (__bf16*)(ws+WS_B_BF);
  float* baseo = (float*)(ws+WS_BASE);

  f32x4 acc[8];

  // ---- stage 1: h = h_in @ embed_w + emb_b (K=32 padded) ----
  bf16x8 aobs;
  #pragma unroll
  for (int j = 0; j < 8; ++j) {
    int k = lgrp*8 + j;
    aobs[j] = (k < 30) ? (__bf16)obs[node*34 + 4 + k] : (__bf16)0.0f;
  }
  #pragma unroll
  for (int nt = 0; nt < 8; ++nt) acc[nt] = (f32x4){0.f,0.f,0.f,0.f};
  #pragma unroll
  for (int nt = 0; nt < 8; ++nt) {
    bf16x8 bw = *(const bf16x8*)(EWT + (nt*16+lid)*32 + lgrp*8);
    acc[nt] = MFMA(aobs, bw, acc[nt]);
  }
  #pragma unroll
  for (int nt = 0; nt < 8; ++nt) {
    int col = nt*16 + lid;
    #pragma unroll
    for (int e = 0; e < 4; ++e) {
      int rl = lgrp*4 + e;
      *(__bf16*)(hw + rl*256 + ((col*2) ^ ((rl&7)<<4))) = (__bf16)(acc[nt][e] + emb_b[col]);
    }
  }
  bf16x8 ah[4];
  #pragma unroll
  for (int ks = 0; ks < 4; ++ks)
    ah[ks] = *(const bf16x8*)(hw + lid*256 + ((ks*64 + lgrp*16) ^ ((lid&7)<<4)));

  // ---- stage 2: A_pre = h @ W1a + edge_b1 -> ws (bf16) ----
  #pragma unroll
  for (int nt = 0; nt < 8; ++nt) acc[nt] = (f32x4){0.f,0.f,0.f,0.f};
  #pragma unroll
  for (int ks = 0; ks < 4; ++ks)
    #pragma unroll
    for (int nt = 0; nt < 8; ++nt) {
      bf16x8 bw = *(const bf16x8*)(W1AT + (nt*16+lid)*128 + ks*32 + lgrp*8);
      acc[nt] = MFMA(ah[ks], bw, acc[nt]);
    }
  #pragma unroll
  for (int nt = 0; nt < 8; ++nt) {
    int col = nt*16 + lid;
    #pragma unroll
    for (int e = 0; e < 4; ++e)
      A_bf[(nb + lgrp*4 + e)*128 + col] = (__bf16)(acc[nt][e] + edge_b1[col]);
  }

  // ---- stage 3: B_pre = h @ W1b -> ws (bf16) ----
  #pragma unroll
  for (int nt = 0; nt < 8; ++nt) acc[nt] = (f32x4){0.f,0.f,0.f,0.f};
  #pragma unroll
  for (int ks = 0; ks < 4; ++ks)
    #pragma unroll
    for (int nt = 0; nt < 8; ++nt) {
      bf16x8 bw = *(const bf16x8*)(W1BT + (nt*16+lid)*128 + ks*32 + lgrp*8);
      acc[nt] = MFMA(ah[ks], bw, acc[nt]);
    }
  #pragma unroll
  for (int nt = 0; nt < 8; ++nt) {
    int col = nt*16 + lid;
    #pragma unroll
    for (int e = 0; e < 4; ++e)
      B_bf[(nb + lgrp*4 + e)*128 + col] = (__bf16)acc[nt][e];
  }

  // ---- stage 4: vel_scale = silu(h@velm_w1 + b1) @ velm_w2 + b2 ----
  #pragma unroll
  for (int nt = 0; nt < 8; ++nt) acc[nt] = (f32x4){0.f,0.f,0.f,0.f};
  #pragma unroll
  for (int ks = 0; ks < 4; ++ks)
    #pragma unroll
    for (int nt = 0; nt < 8; ++nt) {
      bf16x8 bw = *(const bf16x8*)(VW1T + (nt*16+lid)*128 + ks*32 + lgrp*8);
      acc[nt] = MFMA(ah[ks], bw, acc[nt]);
    }
  float pv[4] = {0.f,0.f,0.f,0.f};
  #pragma unroll
  for (int nt = 0; nt < 8; ++nt) {
    int col = nt*16 + lid;
    float w2 = velm_w2[col], b = velm_b1[col];
    #pragma unroll
    for (int e = 0; e < 4; ++e) pv[e] += silu_f(acc[nt][e] + b) * w2;
  }
  #pragma unroll
  for (int d = 1; d < 16; d <<= 1) {
    #pragma unroll
    for (int e = 0; e < 4; ++e) pv[e] += __shfl_xor(pv[e], d, 64);
  }
  float vs[4];
  #pragma unroll
  for (int e = 0; e < 4; ++e) vs[e] = pv[e] + velm_b2[0];

  // ---- stage 5: z1 = silu(obs @ mlp_w1 + b1) (K=64 padded) ----
  bf16x8 az[2];
  #pragma unroll
  for (int ks2 = 0; ks2 < 2; ++ks2)
    #pragma unroll
    for (int j = 0; j < 8; ++j) {
      int k = ks2*32 + lgrp*8 + j;
      az[ks2][j] = (k < 34) ? (__bf16)obs[node*34 + k] : (__bf16)0.0f;
    }
  #pragma unroll
  for (int nt = 0; nt < 8; ++nt) acc[nt] = (f32x4){0.f,0.f,0.f,0.f};
  #pragma unroll
  for (int ks2 = 0; ks2 < 2; ++ks2)
    #pragma unroll
    for (int nt = 0; nt < 8; ++nt) {
      bf16x8 bw = *(const bf16x8*)(MW1T + (nt*16+lid)*64 + ks2*32 + lgrp*8);
      acc[nt] = MFMA(az[ks2], bw, acc[nt]);
    }
  #pragma unroll
  for (int nt = 0; nt < 8; ++nt) {
    int col = nt*16 + lid;
    float b = mlp_b1[col];
    #pragma unroll
    for (int e = 0; e < 4; ++e) {
      int rl = lgrp*4 + e;
      *(__bf16*)(hw + rl*256 + ((col*2) ^ ((rl&7)<<4))) = (__bf16)silu_f(acc[nt][e] + b);
    }
  }
  bf16x8 az1[4];
  #pragma unroll
  for (int ks = 0; ks < 4; ++ks)
    az1[ks] = *(const bf16x8*)(hw + lid*256 + ((ks*64 + lgrp*16) ^ ((lid&7)<<4)));

  // ---- stage 6: z2 = silu(z1@mlp_w2 + b2); o = z2@mlp_w3 ----
  #pragma unroll
  for (int nt = 0; nt < 8; ++nt) acc[nt] = (f32x4){0.f,0.f,0.f,0.f};
  #pragma unroll
  for (int ks = 0; ks < 4; ++ks)
    #pragma unroll
    for (int nt = 0; nt < 8; ++nt) {
      bf16x8 bw = *(const bf16x8*)(MW2T + (nt*16+lid)*128 + ks*32 + lgrp*8);
      acc[nt] = MFMA(az1[ks], bw, acc[nt]);
    }
  float p0[4] = {0.f,0.f,0.f,0.f}, p1[4] = {0.f,0.f,0.f,0.f};
  #pragma unroll
  for (int nt = 0; nt < 8; ++nt) {
    int col = nt*16 + lid;
    float b = mlp_b2[col], w0 = mlp_w3[col*2], w1 = mlp_w3[col*2+1];
    #pragma unroll
    for (int e = 0; e < 4; ++e) {
      float z2 = silu_f(acc[nt][e] + b);
      p0[e] += z2*w0; p1[e] += z2*w1;
    }
  }
  #pragma unroll
  for (int d = 1; d < 16; d <<= 1) {
    #pragma unroll
    for (int e = 0; e < 4; ++e) { p0[e] += __shfl_xor(p0[e], d, 64); p1[e] += __shfl_xor(p1[e], d, 64); }
  }

  // ---- stage 7: base = vel_scale*vel + zMLP out ----
  if (lid == 0) {
    #pragma unroll
    for (int e = 0; e < 4; ++e) {
      int row = nb + lgrp*4 + e;
      float v0 = obs[row*34+2], v1 = obs[row*34+3];
      baseo[row*2+0] = vs[e]*v0 + p0[e] + mlp_b3[0];
      baseo[row*2+1] = vs[e]*v1 + p1[e] + mlp_b3[1];
    }
  }
}

// ---------------- kernel 2: edge chain + aggregation + output -----------------
// 2048 blocks x 256 threads (4 waves). Wave w handles r = t*64 + rblk*4 + w
// versus all 64 c (dense grid; self-edge contributes 0), processed as 4
// sequential 16-edge M-tiles (ct) to keep VGPR low. Single barrier (after
// Bsh staging); msh is per-wave private so waves run free afterwards.
__global__ __launch_bounds__(256, 3) void k_edge(
    const float* __restrict__ obs, const float* __restrict__ eps,
    const float* __restrict__ edge_b2, const float* __restrict__ coord_b1,
    const float* __restrict__ coord_w2, const float* __restrict__ coord_b2,
    const float* __restrict__ log_std,
    const char* __restrict__ ws, float* __restrict__ out) {
  __shared__ __align__(16) char Bsh[16384];     // 64 rows x 256B, XOR-swizzled
  __shared__ __align__(16) char msh_all[4*4096];// per-wave 16 rows x 256B
  __shared__ float locsh[128];
  const int tid = threadIdx.x;
  const int wid = tid>>6, lane = tid&63, lgrp = lane>>4, lid = lane&15;
  const int t = blockIdx.x >> 4, rblk = blockIdx.x & 15;
  const int rl = rblk*4 + wid;
  const int r  = t*64 + rl;
  char* msh = msh_all + wid*4096;

  const __bf16* A_bf = (const __bf16*)(ws+WS_A_BF);
  const __bf16* B_bf = (const __bf16*)(ws+WS_B_BF);
  const __bf16* W2T  = (const __bf16*)(ws+WS_W2T);
  const __bf16* C1T  = (const __bf16*)(ws+WS_C1T);
  const __bf16* W1S  = (const __bf16*)(ws+WS_W1S);
  const float* baseo = (const float*)(ws+WS_BASE);

  // stage B_pre rows for this t into LDS (swizzled), plus loc
  {
    int c = tid >> 2, q = tid & 3;
    const uint4* rowp = (const uint4*)(B_bf + (size_t)(t*64 + c)*128);
    #pragma unroll
    for (int i = 0; i < 4; ++i) {
      uint4 v = rowp[q*4 + i];
      *(uint4*)(Bsh + c*256 + ((q*64 + i*16) ^ ((c&7)<<4))) = v;
    }
    if (tid < 128) {
      int cc = tid >> 1, comp = tid & 1;
      locsh[cc*2+comp] = obs[(size_t)(t*64+cc)*34 + comp];
    }
  }
  __syncthreads();

  // per-wave persistent state
  bf16x8 aA[4], wS[4];
  #pragma unroll
  for (int ks = 0; ks < 4; ++ks) {
    aA[ks] = *(const bf16x8*)(A_bf + (size_t)r*128 + ks*32 + lgrp*8);
    wS[ks] = *(const bf16x8*)(W1S + ks*32 + lgrp*8);
  }
  float b2v[8], cb1v[8], c2v[8];
  #pragma unroll
  for (int nt = 0; nt < 8; ++nt) {
    b2v[nt]  = edge_b2[nt*16+lid];
    cb1v[nt] = coord_b1[nt*16+lid];
    c2v[nt]  = coord_w2[nt*16+lid];
  }
  const float cb2 = coord_b2[0];
  const float lr0 = locsh[rl*2], lr1 = locsh[rl*2+1];

  float agg0 = 0.f, agg1 = 0.f;

  #pragma unroll 1
  for (int ct = 0; ct < 4; ++ct) {
    const int c0 = ct*16;
    // m1 fragment (A-frag layout: row=lid -> edge c0+lid, kchunk=lgrp)
    const int c = c0 + lid;
    float d0 = lr0 - locsh[c*2], d1 = lr1 - locsh[c*2+1];
    float rad = d0*d0 + d1*d1;
    bf16x8 a1[4];
    #pragma unroll
    for (int ks = 0; ks < 4; ++ks) {
      bf16x8 bv = *(const bf16x8*)(Bsh + c*256 + ((ks*64 + lgrp*16) ^ ((c&7)<<4)));
      bf16x8 o;
      #pragma unroll
      for (int j = 0; j < 8; ++j) {
        float f = (float)aA[ks][j] + (float)bv[j] + rad*(float)wS[ks][j];
        o[j] = (__bf16)silu_f(f);
      }
      a1[ks] = o;
    }
    // GEMM1: m2 = m1 @ edge_w2
    f32x4 acc[8];
    #pragma unroll
    for (int nt = 0; nt < 8; ++nt) acc[nt] = (f32x4){0.f,0.f,0.f,0.f};
    #pragma unroll
    for (int ks = 0; ks < 4; ++ks)
      #pragma unroll
      for (int nt = 0; nt < 8; ++nt) {
        bf16x8 bw = *(const bf16x8*)(W2T + (nt*16+lid)*128 + ks*32 + lgrp*8);
        acc[nt] = MFMA(a1[ks], bw, acc[nt]);
      }
    // silu + write to per-wave LDS (transpose to A-frag layout for GEMM2)
    #pragma unroll
    for (int nt = 0; nt < 8; ++nt) {
      int col = nt*16 + lid;
      #pragma unroll
      for (int e = 0; e < 4; ++e) {
        int rlo = lgrp*4 + e;
        *(__bf16*)(msh + rlo*256 + ((col*2) ^ ((rlo&7)<<4))) =
            (__bf16)silu_f(acc[nt][e] + b2v[nt]);
      }
    }
    bf16x8 a2[4];
    #pragma unroll
    for (int ks = 0; ks < 4; ++ks)
      a2[ks] = *(const bf16x8*)(msh + lid*256 + ((ks*64 + lgrp*16) ^ ((lid&7)<<4)));
    // GEMM2: tc = m2 @ coord_w1
    #pragma unroll
    for (int nt = 0; nt < 8; ++nt) acc[nt] = (f32x4){0.f,0.f,0.f,0.f};
    #pragma unroll
    for (int ks = 0; ks < 4; ++ks)
      #pragma unroll
      for (int nt = 0; nt < 8; ++nt) {
        bf16x8 bw = *(const bf16x8*)(C1T + (nt*16+lid)*128 + ks*32 + lgrp*8);
        acc[nt] = MFMA(a2[ks], bw, acc[nt]);
      }
    // epilogue: cw = silu(tc + cb1) . c2 + cb2 ; aggregate diff*cw
    float pcw[4] = {0.f,0.f,0.f,0.f};
    #pragma unroll
    for (int nt = 0; nt < 8; ++nt) {
      #pragma unroll
      for (int e = 0; e < 4; ++e)
        pcw[e] += silu_f(acc[nt][e] + cb1v[nt]) * c2v[nt];
    }
    #pragma unroll
    for (int d = 1; d < 16; d <<= 1) {
      #pragma unroll
      for (int e = 0; e < 4; ++e) pcw[e] += __shfl_xor(pcw[e], d, 64);
    }
    #pragma unroll
    for (int e = 0; e < 4; ++e) {
      int ce = c0 + lgrp*4 + e;
      float cw = pcw[e] + cb2;
      float e0 = lr0 - locsh[ce*2], e1 = lr1 - locsh[ce*2+1];
      float r2 = e0*e0 + e1*e1;
      float s = cw * __builtin_amdgcn_rcpf(__builtin_amdgcn_sqrtf(r2) + 1.0f);
      agg0 += e0*s; agg1 += e1*s;
    }
  }
  // sum partials across the four 16-lane groups (each group holds distinct c)
  agg0 += __shfl_xor(agg0, 16, 64); agg0 += __shfl_xor(agg0, 32, 64);
  agg1 += __shfl_xor(agg1, 16, 64); agg1 += __shfl_xor(agg1, 32, 64);

  if (lane == 0) {
    float mu0 = baseo[r*2+0] + agg0;
    float mu1 = baseo[r*2+1] + agg1;
    float ls0 = log_std[0], ls1 = log_std[1];
    float e0 = eps[r*2+0], e1 = eps[r*2+1];
    const float C = 0.9189385332046727f; // 0.5*log(2*pi)
    out[r*4+0] = mu0 + __expf(ls0)*e0;
    out[r*4+1] = mu1 + __expf(ls1)*e1;
    out[r*4+2] = -0.5f*e0*e0 - ls0 - C;
    out[r*4+3] = -0.5f*e1*e1 - ls1 - C;
  }
}

extern "C" void kernel_launch(void* const* d_in, const int* in_sizes, int n_in,
                              void* d_out, int out_size, void* d_ws, size_t ws_size,
                              hipStream_t stream) {
  const float* obs      = (const float*)d_in[0];
  const float* eps      = (const float*)d_in[1];
  const float* embed_w  = (const float*)d_in[2];
  const float* embed_b  = (const float*)d_in[3];
  const float* edge_w1  = (const float*)d_in[4];
  const float* edge_b1  = (const float*)d_in[5];
  const float* edge_w2  = (const float*)d_in[6];
  const float* edge_b2  = (const float*)d_in[7];
  const float* coord_w1 = (const float*)d_in[8];
  const float* coord_b1 = (const float*)d_in[9];
  const float* coord_w2 = (const float*)d_in[10];
  const float* coord_b2 = (const float*)d_in[11];
  const float* velm_w1  = (const float*)d_in[12];
  const float* velm_b1  = (const float*)d_in[13];
  const float* velm_w2  = (const float*)d_in[14];
  const float* velm_b2  = (const float*)d_in[15];
  const float* mlp_w1   = (const float*)d_in[20];
  const float* mlp_b1   = (const float*)d_in[21];
  const float* mlp_w2   = (const float*)d_in[22];
  const float* mlp_b2   = (const float*)d_in[23];
  const float* mlp_w3   = (const float*)d_in[24];
  const float* mlp_b3   = (const float*)d_in[25];
  const float* log_std  = (const float*)d_in[26];
  char* ws = (char*)d_ws;
  float* out = (float*)d_out;

  hipLaunchKernelGGL(k_prep, dim3(128), dim3(128), 0, stream,
                     edge_w1, edge_w2, coord_w1, velm_w1, mlp_w1, mlp_w2, embed_w, ws);
  hipLaunchKernelGGL(k_node, dim3(128), dim3(256), 0, stream,
                     obs, embed_b, edge_b1, velm_b1, velm_w2, velm_b2,
                     mlp_b1, mlp_b2, mlp_w3, mlp_b3, ws);
  hipLaunchKernelGGL(k_edge, dim3(2048), dim3(256), 0, stream,
                     obs, eps, edge_b2, coord_b1, coord_w2, coord_b2, log_std, ws, out);
}

// Round 3
// 233.372 us; speedup vs baseline: 2.6927x; 2.6927x over previous
//
#include <hip/hip_runtime.h>
#include <hip/hip_bf16.h>

typedef float f32x4 __attribute__((ext_vector_type(4)));
typedef __bf16 bf16x8 __attribute__((ext_vector_type(8)));

#define MFMA(a,b,c) __builtin_amdgcn_mfma_f32_16x16x32_bf16(a,b,c,0,0,0)

// workspace layout (bytes)
#define WS_A_BF   0x000000   // bf16 8192*128  (h@W1a + edge_b1)
#define WS_B_BF   0x200000   // bf16 8192*128  (h@W1b)
#define WS_W2T    0x400000   // bf16 128*128   edge_w2^T
#define WS_C1T    0x408000   // bf16 128*128   coord_w1^T
#define WS_W1AT   0x410000   // bf16 128*128   edge_w1[0:128]^T
#define WS_W1BT   0x418000   // bf16 128*128   edge_w1[128:256]^T
#define WS_VW1T   0x420000   // bf16 128*128   velm_w1^T
#define WS_MW2T   0x428000   // bf16 128*128   mlp_w2^T
#define WS_EWT    0x430000   // bf16 128*32    embed_w^T (K padded 30->32)
#define WS_MW1T   0x432000   // bf16 128*64    mlp_w1^T  (K padded 34->64)
#define WS_W1S    0x436000   // bf16 128       edge_w1 row256+row257
#define WS_BASE   0x436200   // f32 8192*2     vel_scale*vel + zMLP

// fast silu: v_exp + v_rcp (IEEE div was a ~10-instr v_div_* chain)
static __device__ __forceinline__ float silu_f(float x) {
  float e = __expf(-x);
  return x * __builtin_amdgcn_rcpf(1.0f + e);
}

// ---------------- kernel 0: weight prep (transpose to [out][in], bf16) --------
__global__ void k_prep(const float* __restrict__ ew1, const float* __restrict__ ew2,
                       const float* __restrict__ cw1, const float* __restrict__ vw1,
                       const float* __restrict__ mw1, const float* __restrict__ mw2,
                       const float* __restrict__ embw, char* __restrict__ ws) {
  int n = blockIdx.x;   // 0..127 : output row
  int k = threadIdx.x;  // 0..127 : input col
  ((__bf16*)(ws+WS_W2T ))[n*128+k] = (__bf16)ew2[k*128+n];
  ((__bf16*)(ws+WS_C1T ))[n*128+k] = (__bf16)cw1[k*128+n];
  ((__bf16*)(ws+WS_W1AT))[n*128+k] = (__bf16)ew1[k*128+n];
  ((__bf16*)(ws+WS_W1BT))[n*128+k] = (__bf16)ew1[(128+k)*128+n];
  ((__bf16*)(ws+WS_VW1T))[n*128+k] = (__bf16)vw1[k*128+n];
  ((__bf16*)(ws+WS_MW2T))[n*128+k] = (__bf16)mw2[k*128+n];
  if (k < 32) ((__bf16*)(ws+WS_EWT ))[n*32+k] = (k<30) ? (__bf16)embw[k*128+n] : (__bf16)0.0f;
  if (k < 64) ((__bf16*)(ws+WS_MW1T))[n*64+k] = (k<34) ? (__bf16)mw1[k*128+n] : (__bf16)0.0f;
  if (n == 0) ((__bf16*)(ws+WS_W1S))[k] = (__bf16)(ew1[256*128+k] + ew1[257*128+k]);
}

// ---------------- kernel 1: node-level (h, A_pre, B_pre, vel_scale, zMLP) -----
// 128 blocks x 256 threads; each wave handles 16 nodes; hw scratch is per-wave
// private so no barriers.
__global__ __launch_bounds__(256) void k_node(
    const float* __restrict__ obs,
    const float* __restrict__ emb_b,   const float* __restrict__ edge_b1,
    const float* __restrict__ velm_b1, const float* __restrict__ velm_w2,
    const float* __restrict__ velm_b2, const float* __restrict__ mlp_b1,
    const float* __restrict__ mlp_b2,  const float* __restrict__ mlp_w3,
    const float* __restrict__ mlp_b3,  char* __restrict__ ws) {
  __shared__ char hsh_all[4*4096];
  const int tid = threadIdx.x;
  const int wid = tid>>6, lane = tid&63, lgrp = lane>>4, lid = lane&15;
  char* hw = hsh_all + wid*4096;   // 16 rows x 256B per wave
  const int nb = blockIdx.x*64 + wid*16;
  const int node = nb + lid;

  const __bf16* EWT  = (const __bf16*)(ws+WS_EWT);
  const __bf16* W1AT = (const __bf16*)(ws+WS_W1AT);
  const __bf16* W1BT = (const __bf16*)(ws+WS_W1BT);
  const __bf16* VW1T = (const __bf16*)(ws+WS_VW1T);
  const __bf16* MW1T = (const __bf16*)(ws+WS_MW1T);
  const __bf16* MW2T = (const __bf16*)(ws+WS_MW2T);
  __bf16* A_bf = (__bf16*)(ws+WS_A_BF);
  __bf16* B_bf = (__bf16*)(ws+WS_B_BF);
  float* baseo = (float*)(ws+WS_BASE);

  f32x4 acc[8];

  // ---- stage 1: h = h_in @ embed_w + emb_b (K=32 padded) ----
  bf16x8 aobs;
  #pragma unroll
  for (int j = 0; j < 8; ++j) {
    int k = lgrp*8 + j;
    aobs[j] = (k < 30) ? (__bf16)obs[node*34 + 4 + k] : (__bf16)0.0f;
  }
  #pragma unroll
  for (int nt = 0; nt < 8; ++nt) acc[nt] = (f32x4){0.f,0.f,0.f,0.f};
  #pragma unroll
  for (int nt = 0; nt < 8; ++nt) {
    bf16x8 bw = *(const bf16x8*)(EWT + (nt*16+lid)*32 + lgrp*8);
    acc[nt] = MFMA(aobs, bw, acc[nt]);
  }
  #pragma unroll
  for (int nt = 0; nt < 8; ++nt) {
    int col = nt*16 + lid;
    #pragma unroll
    for (int e = 0; e < 4; ++e) {
      int rl = lgrp*4 + e;
      *(__bf16*)(hw + rl*256 + ((col*2) ^ ((rl&7)<<4))) = (__bf16)(acc[nt][e] + emb_b[col]);
    }
  }
  bf16x8 ah[4];
  #pragma unroll
  for (int ks = 0; ks < 4; ++ks)
    ah[ks] = *(const bf16x8*)(hw + lid*256 + ((ks*64 + lgrp*16) ^ ((lid&7)<<4)));

  // ---- stage 2: A_pre = h @ W1a + edge_b1 -> ws (bf16) ----
  #pragma unroll
  for (int nt = 0; nt < 8; ++nt) acc[nt] = (f32x4){0.f,0.f,0.f,0.f};
  #pragma unroll
  for (int ks = 0; ks < 4; ++ks)
    #pragma unroll
    for (int nt = 0; nt < 8; ++nt) {
      bf16x8 bw = *(const bf16x8*)(W1AT + (nt*16+lid)*128 + ks*32 + lgrp*8);
      acc[nt] = MFMA(ah[ks], bw, acc[nt]);
    }
  #pragma unroll
  for (int nt = 0; nt < 8; ++nt) {
    int col = nt*16 + lid;
    #pragma unroll
    for (int e = 0; e < 4; ++e)
      A_bf[(nb + lgrp*4 + e)*128 + col] = (__bf16)(acc[nt][e] + edge_b1[col]);
  }

  // ---- stage 3: B_pre = h @ W1b -> ws (bf16) ----
  #pragma unroll
  for (int nt = 0; nt < 8; ++nt) acc[nt] = (f32x4){0.f,0.f,0.f,0.f};
  #pragma unroll
  for (int ks = 0; ks < 4; ++ks)
    #pragma unroll
    for (int nt = 0; nt < 8; ++nt) {
      bf16x8 bw = *(const bf16x8*)(W1BT + (nt*16+lid)*128 + ks*32 + lgrp*8);
      acc[nt] = MFMA(ah[ks], bw, acc[nt]);
    }
  #pragma unroll
  for (int nt = 0; nt < 8; ++nt) {
    int col = nt*16 + lid;
    #pragma unroll
    for (int e = 0; e < 4; ++e)
      B_bf[(nb + lgrp*4 + e)*128 + col] = (__bf16)acc[nt][e];
  }

  // ---- stage 4: vel_scale = silu(h@velm_w1 + b1) @ velm_w2 + b2 ----
  #pragma unroll
  for (int nt = 0; nt < 8; ++nt) acc[nt] = (f32x4){0.f,0.f,0.f,0.f};
  #pragma unroll
  for (int ks = 0; ks < 4; ++ks)
    #pragma unroll
    for (int nt = 0; nt < 8; ++nt) {
      bf16x8 bw = *(const bf16x8*)(VW1T + (nt*16+lid)*128 + ks*32 + lgrp*8);
      acc[nt] = MFMA(ah[ks], bw, acc[nt]);
    }
  float pv[4] = {0.f,0.f,0.f,0.f};
  #pragma unroll
  for (int nt = 0; nt < 8; ++nt) {
    int col = nt*16 + lid;
    float w2 = velm_w2[col], b = velm_b1[col];
    #pragma unroll
    for (int e = 0; e < 4; ++e) pv[e] += silu_f(acc[nt][e] + b) * w2;
  }
  #pragma unroll
  for (int d = 1; d < 16; d <<= 1) {
    #pragma unroll
    for (int e = 0; e < 4; ++e) pv[e] += __shfl_xor(pv[e], d, 64);
  }
  float vs[4];
  #pragma unroll
  for (int e = 0; e < 4; ++e) vs[e] = pv[e] + velm_b2[0];

  // ---- stage 5: z1 = silu(obs @ mlp_w1 + b1) (K=64 padded) ----
  bf16x8 az[2];
  #pragma unroll
  for (int ks2 = 0; ks2 < 2; ++ks2)
    #pragma unroll
    for (int j = 0; j < 8; ++j) {
      int k = ks2*32 + lgrp*8 + j;
      az[ks2][j] = (k < 34) ? (__bf16)obs[node*34 + k] : (__bf16)0.0f;
    }
  #pragma unroll
  for (int nt = 0; nt < 8; ++nt) acc[nt] = (f32x4){0.f,0.f,0.f,0.f};
  #pragma unroll
  for (int ks2 = 0; ks2 < 2; ++ks2)
    #pragma unroll
    for (int nt = 0; nt < 8; ++nt) {
      bf16x8 bw = *(const bf16x8*)(MW1T + (nt*16+lid)*64 + ks2*32 + lgrp*8);
      acc[nt] = MFMA(az[ks2], bw, acc[nt]);
    }
  #pragma unroll
  for (int nt = 0; nt < 8; ++nt) {
    int col = nt*16 + lid;
    float b = mlp_b1[col];
    #pragma unroll
    for (int e = 0; e < 4; ++e) {
      int rl = lgrp*4 + e;
      *(__bf16*)(hw + rl*256 + ((col*2) ^ ((rl&7)<<4))) = (__bf16)silu_f(acc[nt][e] + b);
    }
  }
  bf16x8 az1[4];
  #pragma unroll
  for (int ks = 0; ks < 4; ++ks)
    az1[ks] = *(const bf16x8*)(hw + lid*256 + ((ks*64 + lgrp*16) ^ ((lid&7)<<4)));

  // ---- stage 6: z2 = silu(z1@mlp_w2 + b2); o = z2@mlp_w3 ----
  #pragma unroll
  for (int nt = 0; nt < 8; ++nt) acc[nt] = (f32x4){0.f,0.f,0.f,0.f};
  #pragma unroll
  for (int ks = 0; ks < 4; ++ks)
    #pragma unroll
    for (int nt = 0; nt < 8; ++nt) {
      bf16x8 bw = *(const bf16x8*)(MW2T + (nt*16+lid)*128 + ks*32 + lgrp*8);
      acc[nt] = MFMA(az1[ks], bw, acc[nt]);
    }
  float p0[4] = {0.f,0.f,0.f,0.f}, p1[4] = {0.f,0.f,0.f,0.f};
  #pragma unroll
  for (int nt = 0; nt < 8; ++nt) {
    int col = nt*16 + lid;
    float b = mlp_b2[col], w0 = mlp_w3[col*2], w1 = mlp_w3[col*2+1];
    #pragma unroll
    for (int e = 0; e < 4; ++e) {
      float z2 = silu_f(acc[nt][e] + b);
      p0[e] += z2*w0; p1[e] += z2*w1;
    }
  }
  #pragma unroll
  for (int d = 1; d < 16; d <<= 1) {
    #pragma unroll
    for (int e = 0; e < 4; ++e) { p0[e] += __shfl_xor(p0[e], d, 64); p1[e] += __shfl_xor(p1[e], d, 64); }
  }

  // ---- stage 7: base = vel_scale*vel + zMLP out ----
  if (lid == 0) {
    #pragma unroll
    for (int e = 0; e < 4; ++e) {
      int row = nb + lgrp*4 + e;
      float v0 = obs[row*34+2], v1 = obs[row*34+3];
      baseo[row*2+0] = vs[e]*v0 + p0[e] + mlp_b3[0];
      baseo[row*2+1] = vs[e]*v1 + p1[e] + mlp_b3[1];
    }
  }
}

// ---------------- kernel 2: edge chain + aggregation + output -----------------
// 2048 blocks x 256 threads (4 waves). Wave w: r = t*64 + rblk*4 + w vs all
// 64 c (dense; self-edge contributes 0), as 2 halves of 32-edge M-tiles.
// ks-outer GEMM loops (unroll 1) keep only 8 weight frags in flight; biases
// and w1s live in LDS -> true register need ~145, so (256,3) holds 3 w/SIMD
// without spilling. Single barrier; msh per-wave private.
__global__ __launch_bounds__(256, 3) void k_edge(
    const float* __restrict__ obs, const float* __restrict__ eps,
    const float* __restrict__ edge_b2, const float* __restrict__ coord_b1,
    const float* __restrict__ coord_w2, const float* __restrict__ coord_b2,
    const float* __restrict__ log_std,
    const char* __restrict__ ws, float* __restrict__ out) {
  __shared__ __align__(16) char Bsh[16384];      // 64 rows x 256B, XOR-swizzled
  __shared__ __align__(16) char msh_all[4*8192]; // per-wave 32 rows x 256B
  __shared__ float locsh[128];
  __shared__ __align__(16) __bf16 wssh[128];     // w1s (bf16)
  __shared__ float b2sh[128], cb1sh[128], c2sh[128];
  const int tid = threadIdx.x;
  const int wid = tid>>6, lane = tid&63, lgrp = lane>>4, lid = lane&15;
  const int t = blockIdx.x >> 4, rblk = blockIdx.x & 15;
  const int rl = rblk*4 + wid;
  const int r  = t*64 + rl;
  char* msh = msh_all + wid*8192;

  const __bf16* A_bf = (const __bf16*)(ws+WS_A_BF);
  const __bf16* B_bf = (const __bf16*)(ws+WS_B_BF);
  const __bf16* W2T  = (const __bf16*)(ws+WS_W2T);
  const __bf16* C1T  = (const __bf16*)(ws+WS_C1T);
  const __bf16* W1S  = (const __bf16*)(ws+WS_W1S);
  const float* baseo = (const float*)(ws+WS_BASE);

  // stage B_pre rows for this t into LDS (swizzled) + loc + consts
  {
    int c = tid >> 2, q = tid & 3;
    const uint4* rowp = (const uint4*)(B_bf + (size_t)(t*64 + c)*128);
    #pragma unroll
    for (int i = 0; i < 4; ++i) {
      uint4 v = rowp[q*4 + i];
      *(uint4*)(Bsh + c*256 + ((q*64 + i*16) ^ ((c&7)<<4))) = v;
    }
    if (tid < 128) {
      int cc = tid >> 1, comp = tid & 1;
      locsh[cc*2+comp] = obs[(size_t)(t*64+cc)*34 + comp];
      wssh[tid]  = W1S[tid];
      b2sh[tid]  = edge_b2[tid];
      cb1sh[tid] = coord_b1[tid];
      c2sh[tid]  = coord_w2[tid];
    }
  }
  __syncthreads();

  // per-wave persistent state (kept minimal)
  bf16x8 aA[4];
  #pragma unroll
  for (int ks = 0; ks < 4; ++ks)
    aA[ks] = *(const bf16x8*)(A_bf + (size_t)r*128 + ks*32 + lgrp*8);
  const float cb2 = coord_b2[0];
  const float lr0 = locsh[rl*2], lr1 = locsh[rl*2+1];

  float agg0 = 0.f, agg1 = 0.f;

  #pragma unroll 1
  for (int half = 0; half < 2; ++half) {
    const int c0 = half*32;
    float rad[2];
    #pragma unroll
    for (int mt = 0; mt < 2; ++mt) {
      int c = c0 + mt*16 + lid;
      float d0 = lr0 - locsh[c*2], d1 = lr1 - locsh[c*2+1];
      rad[mt] = d0*d0 + d1*d1;
    }

    f32x4 acc[2][8];
    #pragma unroll
    for (int mt = 0; mt < 2; ++mt)
      #pragma unroll
      for (int nt = 0; nt < 8; ++nt) acc[mt][nt] = (f32x4){0.f,0.f,0.f,0.f};

    // GEMM1 (ks-outer): a1 computed just-in-time, 8 weight frags in flight
    #pragma unroll 1
    for (int ks = 0; ks < 4; ++ks) {
      bf16x8 wsv = *(const bf16x8*)((const char*)wssh + ks*64 + lgrp*16);
      bf16x8 a1[2];
      #pragma unroll
      for (int mt = 0; mt < 2; ++mt) {
        int c = c0 + mt*16 + lid;
        bf16x8 bv = *(const bf16x8*)(Bsh + c*256 + ((ks*64 + lgrp*16) ^ ((c&7)<<4)));
        bf16x8 o;
        #pragma unroll
        for (int j = 0; j < 8; ++j) {
          float f = (float)aA[ks][j] + (float)bv[j] + rad[mt]*(float)wsv[j];
          o[j] = (__bf16)silu_f(f);
        }
        a1[mt] = o;
      }
      #pragma unroll
      for (int nt = 0; nt < 8; ++nt) {
        bf16x8 bw = *(const bf16x8*)(W2T + (nt*16+lid)*128 + ks*32 + lgrp*8);
        acc[0][nt] = MFMA(a1[0], bw, acc[0][nt]);
        acc[1][nt] = MFMA(a1[1], bw, acc[1][nt]);
      }
    }

    // silu + write to per-wave LDS (transpose to A-frag layout for GEMM2)
    #pragma unroll
    for (int nt = 0; nt < 8; ++nt) {
      int col = nt*16 + lid;
      float b = b2sh[col];
      #pragma unroll
      for (int mt = 0; mt < 2; ++mt)
        #pragma unroll
        for (int e = 0; e < 4; ++e) {
          int rlo = mt*16 + lgrp*4 + e;
          *(__bf16*)(msh + rlo*256 + ((col*2) ^ ((rlo&7)<<4))) =
              (__bf16)silu_f(acc[mt][nt][e] + b);
        }
    }

    #pragma unroll
    for (int mt = 0; mt < 2; ++mt)
      #pragma unroll
      for (int nt = 0; nt < 8; ++nt) acc[mt][nt] = (f32x4){0.f,0.f,0.f,0.f};

    // GEMM2 (ks-outer): a2 read just-in-time from msh
    #pragma unroll 1
    for (int ks = 0; ks < 4; ++ks) {
      bf16x8 a2[2];
      #pragma unroll
      for (int mt = 0; mt < 2; ++mt) {
        int rlo = mt*16 + lid;
        a2[mt] = *(const bf16x8*)(msh + rlo*256 + ((ks*64 + lgrp*16) ^ ((rlo&7)<<4)));
      }
      #pragma unroll
      for (int nt = 0; nt < 8; ++nt) {
        bf16x8 bw = *(const bf16x8*)(C1T + (nt*16+lid)*128 + ks*32 + lgrp*8);
        acc[0][nt] = MFMA(a2[0], bw, acc[0][nt]);
        acc[1][nt] = MFMA(a2[1], bw, acc[1][nt]);
      }
    }

    // epilogue: cw = silu(tc + cb1) . c2 + cb2 ; aggregate diff*cw
    float pcw[2][4];
    #pragma unroll
    for (int mt = 0; mt < 2; ++mt)
      #pragma unroll
      for (int e = 0; e < 4; ++e) pcw[mt][e] = 0.f;
    #pragma unroll
    for (int nt = 0; nt < 8; ++nt) {
      int col = nt*16 + lid;
      float cb1 = cb1sh[col], c2 = c2sh[col];
      #pragma unroll
      for (int mt = 0; mt < 2; ++mt)
        #pragma unroll
        for (int e = 0; e < 4; ++e)
          pcw[mt][e] += silu_f(acc[mt][nt][e] + cb1) * c2;
    }
    #pragma unroll
    for (int d = 1; d < 16; d <<= 1) {
      #pragma unroll
      for (int mt = 0; mt < 2; ++mt)
        #pragma unroll
        for (int e = 0; e < 4; ++e) pcw[mt][e] += __shfl_xor(pcw[mt][e], d, 64);
    }
    #pragma unroll
    for (int mt = 0; mt < 2; ++mt)
      #pragma unroll
      for (int e = 0; e < 4; ++e) {
        int ce = c0 + mt*16 + lgrp*4 + e;
        float cw = pcw[mt][e] + cb2;
        float e0 = lr0 - locsh[ce*2], e1 = lr1 - locsh[ce*2+1];
        float r2 = e0*e0 + e1*e1;
        float s = cw * __builtin_amdgcn_rcpf(__builtin_amdgcn_sqrtf(r2) + 1.0f);
        agg0 += e0*s; agg1 += e1*s;
      }
  }
  // sum partials across the four 16-lane groups
  agg0 += __shfl_xor(agg0, 16, 64); agg0 += __shfl_xor(agg0, 32, 64);
  agg1 += __shfl_xor(agg1, 16, 64); agg1 += __shfl_xor(agg1, 32, 64);

  if (lane == 0) {
    float mu0 = baseo[r*2+0] + agg0;
    float mu1 = baseo[r*2+1] + agg1;
    float ls0 = log_std[0], ls1 = log_std[1];
    float e0 = eps[r*2+0], e1 = eps[r*2+1];
    const float C = 0.9189385332046727f; // 0.5*log(2*pi)
    out[r*4+0] = mu0 + __expf(ls0)*e0;
    out[r*4+1] = mu1 + __expf(ls1)*e1;
    out[r*4+2] = -0.5f*e0*e0 - ls0 - C;
    out[r*4+3] = -0.5f*e1*e1 - ls1 - C;
  }
}

extern "C" void kernel_launch(void* const* d_in, const int* in_sizes, int n_in,
                              void* d_out, int out_size, void* d_ws, size_t ws_size,
                              hipStream_t stream) {
  const float* obs      = (const float*)d_in[0];
  const float* eps      = (const float*)d_in[1];
  const float* embed_w  = (const float*)d_in[2];
  const float* embed_b  = (const float*)d_in[3];
  const float* edge_w1  = (const float*)d_in[4];
  const float* edge_b1  = (const float*)d_in[5];
  const float* edge_w2  = (const float*)d_in[6];
  const float* edge_b2  = (const float*)d_in[7];
  const float* coord_w1 = (const float*)d_in[8];
  const float* coord_b1 = (const float*)d_in[9];
  const float* coord_w2 = (const float*)d_in[10];
  const float* coord_b2 = (const float*)d_in[11];
  const float* velm_w1  = (const float*)d_in[12];
  const float* velm_b1  = (const float*)d_in[13];
  const float* velm_w2  = (const float*)d_in[14];
  const float* velm_b2  = (const float*)d_in[15];
  const float* mlp_w1   = (const float*)d_in[20];
  const float* mlp_b1   = (const float*)d_in[21];
  const float* mlp_w2   = (const float*)d_in[22];
  const float* mlp_b2   = (const float*)d_in[23];
  const float* mlp_w3   = (const float*)d_in[24];
  const float* mlp_b3   = (const float*)d_in[25];
  const float* log_std  = (const float*)d_in[26];
  char* ws = (char*)d_ws;
  float* out = (float*)d_out;

  hipLaunchKernelGGL(k_prep, dim3(128), dim3(128), 0, stream,
                     edge_w1, edge_w2, coord_w1, velm_w1, mlp_w1, mlp_w2, embed_w, ws);
  hipLaunchKernelGGL(k_node, dim3(128), dim3(256), 0, stream,
                     obs, embed_b, edge_b1, velm_b1, velm_w2, velm_b2,
                     mlp_b1, mlp_b2, mlp_w3, mlp_b3, ws);
  hipLaunchKernelGGL(k_edge, dim3(2048), dim3(256), 0, stream,
                     obs, eps, edge_b2, coord_b1, coord_w2, coord_b2, log_std, ws, out);
}